// Round 1
// baseline (4786.679 us; speedup 1.0000x reference)
//
#include <hip/hip_runtime.h>
#include <cstddef>

#define T_STEPS  512
#define D_IN     5
#define NB       16      // batch elements per block
#define NTHREADS 512     // 8 waves: threads 0-255 = layer0 gates, 256-511 = layer1 gates

__device__ __forceinline__ float fast_sigmoid(float x) {
    return __fdividef(1.0f, 1.0f + __expf(-x));
}
__device__ __forceinline__ float fast_tanh(float x) {
    // tanh(x) = 1 - 2/(1+e^{2x}); saturates correctly for |x| large
    return 1.0f - __fdividef(2.0f, 1.0f + __expf(2.0f * x));
}

__global__ __launch_bounds__(NTHREADS, 2)
void lstm_stack_fused(const float* __restrict__ x,
                      const float* __restrict__ W_ih0,
                      const float* __restrict__ W_hh0,
                      const float* __restrict__ b_ih0,
                      const float* __restrict__ b_hh0,
                      const float* __restrict__ W_ih1,
                      const float* __restrict__ W_hh1,
                      const float* __restrict__ b_ih1,
                      const float* __restrict__ b_hh1,
                      const float* __restrict__ W1,
                      const float* __restrict__ b1,
                      const float* __restrict__ W2,
                      const float* __restrict__ b2,
                      float* __restrict__ out)
{
    // hcat[b][0:64) = h1 state, hcat[b][64:128) = h2 state
    __shared__ alignas(16) float hcat[NB][128];
    __shared__ alignas(16) float gbuf0[NB][256];   // layer0 gate pre-activations
    __shared__ alignas(16) float gbuf1[NB][256];   // layer1 gate pre-activations
    __shared__ float xbuf[NB][D_IN];               // staged x[:, s, :]

    const int tid  = threadIdx.x;
    const int b0   = blockIdx.x * NB;
    const bool isL0 = (tid < 256);
    const int g    = isL0 ? tid : (tid - 256);

    // ---- persistent register state ----
    float wreg[128];          // L0: W_hh0 row (64 used); L1: [W_ih1 row | W_hh1 row]
    float wih0r[D_IN];        // L0 only
    float biasr;
    float cst[4] = {0.f, 0.f, 0.f, 0.f};  // cell state for the 4 (b,u) items this thread updates

    if (isL0) {
        #pragma unroll
        for (int j = 0; j < 64; ++j) wreg[j] = W_hh0[g * 64 + j];
        #pragma unroll
        for (int d = 0; d < D_IN; ++d) wih0r[d] = W_ih0[g * D_IN + d];
        biasr = b_ih0[g] + b_hh0[g];
    } else {
        #pragma unroll
        for (int j = 0; j < 64; ++j) wreg[j]      = W_ih1[g * 64 + j];
        #pragma unroll
        for (int j = 0; j < 64; ++j) wreg[64 + j] = W_hh1[g * 64 + j];
        #pragma unroll
        for (int d = 0; d < D_IN; ++d) wih0r[d] = 0.f;
        biasr = b_ih1[g] + b_hh1[g];
    }

    // zero initial h state, stage x[:, 0, :]
    for (int i = tid; i < NB * 128; i += NTHREADS) (&hcat[0][0])[i] = 0.f;
    if (tid < NB * D_IN) {
        const int bb = tid / D_IN, d = tid % D_IN;
        xbuf[bb][d] = x[((size_t)(b0 + bb) * T_STEPS) * D_IN + d];
    }
    __syncthreads();

    // Pipelined: iter s -> phase A: gates0(s) [L0] || gates1(s-1) [L1]
    //                     phase B: h1(s),c1   [L0] || h2(s-1),c2  [L1]
    for (int s = 0; s <= T_STEPS; ++s) {
        // ---------------- phase A: gate matvecs ----------------
        if (isL0) {
            if (s < T_STEPS) {
                #pragma unroll
                for (int bq = 0; bq < 4; ++bq) {
                    float acc[4];
                    #pragma unroll
                    for (int i = 0; i < 4; ++i) {
                        const int b = bq * 4 + i;
                        float a = biasr;
                        #pragma unroll
                        for (int d = 0; d < D_IN; ++d) a = fmaf(wih0r[d], xbuf[b][d], a);
                        acc[i] = a;
                    }
                    #pragma unroll
                    for (int j4 = 0; j4 < 16; ++j4) {
                        #pragma unroll
                        for (int i = 0; i < 4; ++i) {
                            const float4 h4 = *reinterpret_cast<const float4*>(&hcat[bq * 4 + i][j4 * 4]);
                            float a = acc[i];
                            a = fmaf(wreg[j4 * 4 + 0], h4.x, a);
                            a = fmaf(wreg[j4 * 4 + 1], h4.y, a);
                            a = fmaf(wreg[j4 * 4 + 2], h4.z, a);
                            a = fmaf(wreg[j4 * 4 + 3], h4.w, a);
                            acc[i] = a;
                        }
                    }
                    #pragma unroll
                    for (int i = 0; i < 4; ++i) gbuf0[bq * 4 + i][g] = acc[i];
                }
            }
        } else {
            if (s > 0) {
                #pragma unroll
                for (int bq = 0; bq < 4; ++bq) {
                    float acc[4] = {biasr, biasr, biasr, biasr};
                    #pragma unroll
                    for (int j4 = 0; j4 < 32; ++j4) {   // j 0..127 over [h1 ; h2]
                        #pragma unroll
                        for (int i = 0; i < 4; ++i) {
                            const float4 h4 = *reinterpret_cast<const float4*>(&hcat[bq * 4 + i][j4 * 4]);
                            float a = acc[i];
                            a = fmaf(wreg[j4 * 4 + 0], h4.x, a);
                            a = fmaf(wreg[j4 * 4 + 1], h4.y, a);
                            a = fmaf(wreg[j4 * 4 + 2], h4.z, a);
                            a = fmaf(wreg[j4 * 4 + 3], h4.w, a);
                            acc[i] = a;
                        }
                    }
                    #pragma unroll
                    for (int i = 0; i < 4; ++i) gbuf1[bq * 4 + i][g] = acc[i];
                }
            }
        }
        __syncthreads();

        // ---------------- phase B: activations + state update ----------------
        if (isL0) {
            if (s < T_STEPS) {
                const int u  = tid & 63;
                const int bs = tid >> 6;
                #pragma unroll
                for (int bb = 0; bb < 4; ++bb) {
                    const int b = bs * 4 + bb;
                    const float gi = gbuf0[b][u];
                    const float gf = gbuf0[b][u + 64];
                    const float gg = gbuf0[b][u + 128];
                    const float go = gbuf0[b][u + 192];
                    const float c  = fast_sigmoid(gf) * cst[bb] + fast_sigmoid(gi) * fast_tanh(gg);
                    cst[bb] = c;
                    hcat[b][u] = fast_sigmoid(go) * fast_tanh(c);
                }
            }
            // stage x for step s+1
            if (tid < NB * D_IN && (s + 1) < T_STEPS) {
                const int bb = tid / D_IN, d = tid % D_IN;
                xbuf[bb][d] = x[((size_t)(b0 + bb) * T_STEPS + (s + 1)) * D_IN + d];
            }
        } else {
            if (s > 0) {
                const int u  = (tid - 256) & 63;
                const int bs = (tid - 256) >> 6;
                #pragma unroll
                for (int bb = 0; bb < 4; ++bb) {
                    const int b = bs * 4 + bb;
                    const float gi = gbuf1[b][u];
                    const float gf = gbuf1[b][u + 64];
                    const float gg = gbuf1[b][u + 128];
                    const float go = gbuf1[b][u + 192];
                    const float c  = fast_sigmoid(gf) * cst[bb] + fast_sigmoid(gi) * fast_tanh(gg);
                    cst[bb] = c;
                    hcat[b][64 + u] = fast_sigmoid(go) * fast_tanh(c);
                }
            }
        }
        __syncthreads();
    }

    // ---------------- FC head: relu(h2_T @ W1^T + b1) @ W2^T + b2 ----------------
    {
        const int bb = tid >> 5;   // 0..15
        const int k  = tid & 31;   // 0..31
        float a = b1[k];
        const float4* w1p = reinterpret_cast<const float4*>(W1 + k * 64);
        #pragma unroll
        for (int j4 = 0; j4 < 16; ++j4) {
            const float4 w4 = w1p[j4];
            const float4 h4 = *reinterpret_cast<const float4*>(&hcat[bb][64 + j4 * 4]);
            a = fmaf(w4.x, h4.x, a);
            a = fmaf(w4.y, h4.y, a);
            a = fmaf(w4.z, h4.z, a);
            a = fmaf(w4.w, h4.w, a);
        }
        gbuf0[bb][k] = fmaxf(a, 0.0f);   // reuse gbuf0 as z buffer
    }
    __syncthreads();
    if (tid < NB) {
        float a = b2[0];
        #pragma unroll
        for (int k = 0; k < 32; ++k) a = fmaf(W2[k], gbuf0[tid][k], a);
        out[b0 + tid] = a;
    }
}

extern "C" void kernel_launch(void* const* d_in, const int* in_sizes, int n_in,
                              void* d_out, int out_size, void* d_ws, size_t ws_size,
                              hipStream_t stream) {
    (void)in_sizes; (void)n_in; (void)d_ws; (void)ws_size;
    const float* xp     = (const float*)d_in[0];
    const float* W_ih0  = (const float*)d_in[1];
    const float* W_hh0  = (const float*)d_in[2];
    const float* b_ih0  = (const float*)d_in[3];
    const float* b_hh0  = (const float*)d_in[4];
    const float* W_ih1  = (const float*)d_in[5];
    const float* W_hh1  = (const float*)d_in[6];
    const float* b_ih1  = (const float*)d_in[7];
    const float* b_hh1  = (const float*)d_in[8];
    const float* W1     = (const float*)d_in[9];
    const float* b1     = (const float*)d_in[10];
    const float* W2     = (const float*)d_in[11];
    const float* b2     = (const float*)d_in[12];
    float* outp = (float*)d_out;

    const int nblocks = out_size / NB;   // 4096/16 = 256, one block per CU
    hipLaunchKernelGGL(lstm_stack_fused, dim3(nblocks), dim3(NTHREADS), 0, stream,
                       xp, W_ih0, W_hh0, b_ih0, b_hh0,
                       W_ih1, W_hh1, b_ih1, b_hh1,
                       W1, b1, W2, b2, outp);
}

// Round 2
// 1280.644 us; speedup vs baseline: 3.7377x; 3.7377x over previous
//
#include <hip/hip_runtime.h>
#include <cstddef>

#define T_STEPS  512
#define D_IN     5
#define NB       16      // batch elements per block
#define NTHREADS 512     // 8 waves; each wave owns 2 L0 M-tiles + 2 L1 M-tiles

typedef __attribute__((ext_vector_type(8))) short bf16x8;   // 8 bf16 (4 VGPRs)
typedef __attribute__((ext_vector_type(4))) float f32x4;    // MFMA C/D

#define MFMA(a, b, c) __builtin_amdgcn_mfma_f32_16x16x32_bf16((a), (b), (c), 0, 0, 0)

__device__ __forceinline__ float fast_sigmoid(float x) {
    return __fdividef(1.0f, 1.0f + __expf(-x));
}
__device__ __forceinline__ float fast_tanh(float x) {
    return 1.0f - __fdividef(2.0f, 1.0f + __expf(2.0f * x));
}

__device__ __forceinline__ unsigned short f2bf(float f) {   // RTNE fp32->bf16 bits
    unsigned int u = __float_as_uint(f);
    u += 0x7FFFu + ((u >> 16) & 1u);
    return (unsigned short)(u >> 16);
}
__device__ __forceinline__ float bf2f(unsigned short h) {
    return __uint_as_float(((unsigned int)h) << 16);
}
__device__ __forceinline__ void split8(const float* wv, bf16x8& hi, bf16x8& lo) {
    #pragma unroll
    for (int j = 0; j < 8; ++j) {
        unsigned short h = f2bf(wv[j]);
        unsigned short l = f2bf(wv[j] - bf2f(h));
        hi[j] = (short)h;
        lo[j] = (short)l;
    }
}

__global__ __launch_bounds__(NTHREADS, 2)
void lstm_stack_mfma(const float* __restrict__ x,
                     const float* __restrict__ W_ih0,
                     const float* __restrict__ W_hh0,
                     const float* __restrict__ b_ih0,
                     const float* __restrict__ b_hh0,
                     const float* __restrict__ W_ih1,
                     const float* __restrict__ W_hh1,
                     const float* __restrict__ b_ih1,
                     const float* __restrict__ b_hh1,
                     const float* __restrict__ W1,
                     const float* __restrict__ b1,
                     const float* __restrict__ W2,
                     const float* __restrict__ b2,
                     float* __restrict__ out)
{
    // h planes, n-major so a B-fragment (8 consecutive k for fixed n) is one ds_read_b128.
    // k 0..63 = h1, 64..127 = h2, 128..135 pad (stride 136 u16 = 68 dw -> bank step 4 -> 2-way, free)
    __shared__ alignas(16) unsigned short hcat_hi[NB][136];
    __shared__ alignas(16) unsigned short hcat_lo[NB][136];
    // x tile, k 0..4 = x, rest zero (stride 40 u16 = 80 B, 16B-aligned rows, bank step 20 -> 2-way)
    __shared__ alignas(16) unsigned short xp_hi[NB][40];
    __shared__ alignas(16) unsigned short xp_lo[NB][40];
    // gate pre-activations [b][g]; stride 260 dw -> bank step 4 -> 2-way, rows 16B-aligned
    __shared__ alignas(16) float gb0[NB][260];
    __shared__ alignas(16) float gb1[NB][260];

    const int tid  = threadIdx.x;
    const int b0   = blockIdx.x * NB;
    const int w    = tid >> 6;        // wave 0..7
    const int lane = tid & 63;
    const int n16  = lane & 15;       // B col n / A row m / C col n
    const int quad = lane >> 4;       // 0..3

    // ---------------- persistent register state ----------------
    bf16x8 aXh[2], aXl[2];            // L0 x K-tile (k=0..31, only 0..4 nonzero)
    bf16x8 a0h[2][2], a0l[2][2];      // L0 h1 K-tiles (k0 = 0, 32)
    bf16x8 a1h[2][4], a1l[2][4];      // L1 K-tiles (k0 = 0,32,64,96 over [h1;h2])
    f32x4  bc0[2], bc1[2];            // bias as C-init fragments
    float  cst0[4] = {0.f, 0.f, 0.f, 0.f};   // L0 cell state (threads 0-255)
    float  cst1[4] = {0.f, 0.f, 0.f, 0.f};   // L1 cell state (threads 256-511)

    #pragma unroll
    for (int t = 0; t < 2; ++t) {
        const int Mt = w * 2 + t;           // M-tile 0..15
        const int M  = Mt * 16 + n16;       // A row m = lane&15
        float wv[8];
        // x K-tile: A[m][k] = W_ih0[m][k] for k<5 else 0
        #pragma unroll
        for (int j = 0; j < 8; ++j) {
            const int k = quad * 8 + j;
            wv[j] = (k < D_IN) ? W_ih0[M * D_IN + k] : 0.f;
        }
        split8(wv, aXh[t], aXl[t]);
        // L0 h1 K-tiles
        #pragma unroll
        for (int kt = 0; kt < 2; ++kt) {
            #pragma unroll
            for (int j = 0; j < 8; ++j) wv[j] = W_hh0[M * 64 + kt * 32 + quad * 8 + j];
            split8(wv, a0h[t][kt], a0l[t][kt]);
        }
        // L1 K-tiles: k<64 -> W_ih1 (input h1), k>=64 -> W_hh1 (recurrent h2)
        #pragma unroll
        for (int kt = 0; kt < 4; ++kt) {
            const int kg = kt * 32 + quad * 8;
            #pragma unroll
            for (int j = 0; j < 8; ++j)
                wv[j] = (kg < 64) ? W_ih1[M * 64 + kg + j] : W_hh1[M * 64 + (kg - 64) + j];
            split8(wv, a1h[t][kt], a1l[t][kt]);
        }
        // bias C-init: C/D row = quad*4 + r, col = n16
        #pragma unroll
        for (int r = 0; r < 4; ++r) {
            const int g = Mt * 16 + quad * 4 + r;
            bc0[t][r] = b_ih0[g] + b_hh0[g];
            bc1[t][r] = b_ih1[g] + b_hh1[g];
        }
    }

    // ---------------- LDS init (disjoint writes, one barrier) ----------------
    for (int i = tid; i < NB * 136; i += NTHREADS) {
        (&hcat_hi[0][0])[i] = 0;
        (&hcat_lo[0][0])[i] = 0;
    }
    for (int i = tid; i < NB * 40; i += NTHREADS) {
        const int c = i % 40;
        if (c >= D_IN) { (&xp_hi[0][0])[i] = 0; (&xp_lo[0][0])[i] = 0; }
    }
    if (tid < NB * D_IN) {   // x(t=0)
        const int bb = tid / D_IN, d = tid % D_IN;
        const float xv = x[((size_t)(b0 + bb) * T_STEPS) * D_IN + d];
        const unsigned short xh = f2bf(xv);
        xp_hi[bb][d] = xh;
        xp_lo[bb][d] = f2bf(xv - bf2f(xh));
    }
    __syncthreads();

    // Pipelined: step s phase A: gates0(s) and gates1(s-1) via MFMA (all waves, uniform)
    //            step s phase B: h1(s)/c1 update + h2(s-1)/c2 update + x(s+1) staging
    for (int s = 0; s <= T_STEPS; ++s) {
        // ---- phase A ----
        float xv = 0.f;
        int xb = 0, xd = 0;
        if (tid < NB * D_IN) {          // prefetch x(s+1) early, consumed in phase B
            xb = tid / D_IN; xd = tid % D_IN;
            if (s + 1 < T_STEPS)
                xv = x[((size_t)(b0 + xb) * T_STEPS + (s + 1)) * D_IN + xd];
        }

        const bf16x8 bxh = *reinterpret_cast<const bf16x8*>(&xp_hi[n16][quad * 8]);
        const bf16x8 bxl = *reinterpret_cast<const bf16x8*>(&xp_lo[n16][quad * 8]);
        bf16x8 bhh[4], bhl[4];
        #pragma unroll
        for (int kt = 0; kt < 4; ++kt) {
            bhh[kt] = *reinterpret_cast<const bf16x8*>(&hcat_hi[n16][kt * 32 + quad * 8]);
            bhl[kt] = *reinterpret_cast<const bf16x8*>(&hcat_lo[n16][kt * 32 + quad * 8]);
        }

        #pragma unroll
        for (int t = 0; t < 2; ++t) {
            const int col = (w * 2 + t) * 16 + quad * 4;
            f32x4 acc = bc0[t];
            acc = MFMA(aXl[t], bxh, acc);
            acc = MFMA(aXh[t], bxl, acc);
            acc = MFMA(aXh[t], bxh, acc);
            #pragma unroll
            for (int kt = 0; kt < 2; ++kt) {
                acc = MFMA(a0l[t][kt], bhh[kt], acc);
                acc = MFMA(a0h[t][kt], bhl[kt], acc);
                acc = MFMA(a0h[t][kt], bhh[kt], acc);
            }
            *reinterpret_cast<f32x4*>(&gb0[n16][col]) = acc;

            f32x4 acc1 = bc1[t];
            #pragma unroll
            for (int kt = 0; kt < 4; ++kt) {
                acc1 = MFMA(a1l[t][kt], bhh[kt], acc1);
                acc1 = MFMA(a1h[t][kt], bhl[kt], acc1);
                acc1 = MFMA(a1h[t][kt], bhh[kt], acc1);
            }
            *reinterpret_cast<f32x4*>(&gb1[n16][col]) = acc1;
        }
        __syncthreads();

        // ---- phase B ----
        if (s < T_STEPS && tid < 256) {          // L0 update: h1(s), c1
            const int u = tid & 63, bs = tid >> 6;
            #pragma unroll
            for (int bb = 0; bb < 4; ++bb) {
                const int b = bs * 4 + bb;
                const float gi = gb0[b][u];
                const float gf = gb0[b][64 + u];
                const float gg = gb0[b][128 + u];
                const float go = gb0[b][192 + u];
                const float c  = fast_sigmoid(gf) * cst0[bb] + fast_sigmoid(gi) * fast_tanh(gg);
                cst0[bb] = c;
                const float h  = fast_sigmoid(go) * fast_tanh(c);
                const unsigned short hh = f2bf(h);
                hcat_hi[b][u] = hh;
                hcat_lo[b][u] = f2bf(h - bf2f(hh));
            }
        }
        if (s > 0 && tid >= 256) {               // L1 update: h2(s-1), c2
            const int t2 = tid - 256;
            const int u = t2 & 63, bs = t2 >> 6;
            #pragma unroll
            for (int bb = 0; bb < 4; ++bb) {
                const int b = bs * 4 + bb;
                const float gi = gb1[b][u];
                const float gf = gb1[b][64 + u];
                const float gg = gb1[b][128 + u];
                const float go = gb1[b][192 + u];
                const float c  = fast_sigmoid(gf) * cst1[bb] + fast_sigmoid(gi) * fast_tanh(gg);
                cst1[bb] = c;
                const float h  = fast_sigmoid(go) * fast_tanh(c);
                const unsigned short hh = f2bf(h);
                hcat_hi[b][64 + u] = hh;
                hcat_lo[b][64 + u] = f2bf(h - bf2f(hh));
            }
        }
        if (tid < NB * D_IN && s + 1 < T_STEPS) { // stage x(s+1)
            const unsigned short xh = f2bf(xv);
            xp_hi[xb][xd] = xh;
            xp_lo[xb][xd] = f2bf(xv - bf2f(xh));
        }
        __syncthreads();
    }

    // ---------------- FC head: relu(h2_T @ W1^T + b1) @ W2^T + b2 ----------------
    {
        const int bb = tid >> 5;   // 0..15
        const int k  = tid & 31;   // 0..31
        float a = b1[k];
        #pragma unroll 16
        for (int j = 0; j < 64; ++j) {
            const float h = bf2f(hcat_hi[bb][64 + j]) + bf2f(hcat_lo[bb][64 + j]);
            a = fmaf(W1[k * 64 + j], h, a);
        }
        gb0[bb][k] = fmaxf(a, 0.0f);   // reuse gb0 as z buffer
    }
    __syncthreads();
    if (tid < NB) {
        float a = b2[0];
        #pragma unroll
        for (int k = 0; k < 32; ++k) a = fmaf(W2[k], gb0[tid][k], a);
        out[b0 + tid] = a;
    }
}

extern "C" void kernel_launch(void* const* d_in, const int* in_sizes, int n_in,
                              void* d_out, int out_size, void* d_ws, size_t ws_size,
                              hipStream_t stream) {
    (void)in_sizes; (void)n_in; (void)d_ws; (void)ws_size;
    const float* xp     = (const float*)d_in[0];
    const float* W_ih0  = (const float*)d_in[1];
    const float* W_hh0  = (const float*)d_in[2];
    const float* b_ih0  = (const float*)d_in[3];
    const float* b_hh0  = (const float*)d_in[4];
    const float* W_ih1  = (const float*)d_in[5];
    const float* W_hh1  = (const float*)d_in[6];
    const float* b_ih1  = (const float*)d_in[7];
    const float* b_hh1  = (const float*)d_in[8];
    const float* W1     = (const float*)d_in[9];
    const float* b1     = (const float*)d_in[10];
    const float* W2     = (const float*)d_in[11];
    const float* b2     = (const float*)d_in[12];
    float* outp = (float*)d_out;

    const int nblocks = out_size / NB;   // 4096/16 = 256, one block per CU
    hipLaunchKernelGGL(lstm_stack_mfma, dim3(nblocks), dim3(NTHREADS), 0, stream,
                       xp, W_ih0, W_hh0, b_ih0, b_hh0,
                       W_ih1, W_hh1, b_ih1, b_hh1,
                       W1, b1, W2, b2, outp);
}

// Round 3
// 1113.510 us; speedup vs baseline: 4.2987x; 1.1501x over previous
//
#include <hip/hip_runtime.h>
#include <cstddef>

#define T_STEPS  512
#define D_IN     5
#define NB       16      // batch elements per block
#define NTHREADS 512     // 8 waves; each wave owns 2 L0 M-tiles + 2 L1 M-tiles

typedef __attribute__((ext_vector_type(8))) short bf16x8;   // 8 bf16 (4 VGPRs)
typedef __attribute__((ext_vector_type(4))) float f32x4;    // MFMA C/D

#define MFMA(a, b, c) __builtin_amdgcn_mfma_f32_16x16x32_bf16((a), (b), (c), 0, 0, 0)

__device__ __forceinline__ float fast_sigmoid(float x) {
    return __fdividef(1.0f, 1.0f + __expf(-x));
}
__device__ __forceinline__ float fast_tanh(float x) {
    return 1.0f - __fdividef(2.0f, 1.0f + __expf(2.0f * x));
}

__device__ __forceinline__ unsigned short f2bf(float f) {   // RTNE fp32->bf16 bits
    unsigned int u = __float_as_uint(f);
    u += 0x7FFFu + ((u >> 16) & 1u);
    return (unsigned short)(u >> 16);
}
__device__ __forceinline__ float bf2f(unsigned short h) {
    return __uint_as_float(((unsigned int)h) << 16);
}
__device__ __forceinline__ void split8(const float* wv, bf16x8& hi, bf16x8& lo) {
    #pragma unroll
    for (int j = 0; j < 8; ++j) {
        unsigned short h = f2bf(wv[j]);
        unsigned short l = f2bf(wv[j] - bf2f(h));
        hi[j] = (short)h;
        lo[j] = (short)l;
    }
}

// Gate-row permutation: MFMA row m corresponds to (u = m/4, gate = m%4),
// i.e. original weight row gate*64 + u. With C/D layout col=lane&15,
// row=quad*4+r, each lane's f32x4 acc holds (i,f,g,o) for ONE (u,b) pair:
// the LSTM cell update is register-local -- no gate LDS round-trip.

__global__ __launch_bounds__(NTHREADS, 2)
void lstm_stack_mfma2(const float* __restrict__ x,
                      const float* __restrict__ W_ih0,
                      const float* __restrict__ W_hh0,
                      const float* __restrict__ b_ih0,
                      const float* __restrict__ b_hh0,
                      const float* __restrict__ W_ih1,
                      const float* __restrict__ W_hh1,
                      const float* __restrict__ b_ih1,
                      const float* __restrict__ b_hh1,
                      const float* __restrict__ W1,
                      const float* __restrict__ b1,
                      const float* __restrict__ W2,
                      const float* __restrict__ b2,
                      float* __restrict__ out)
{
    // Double-buffered h planes (k 0..63 = h1, 64..127 = h2; stride 136 u16)
    __shared__ alignas(16) unsigned short h_hi[2][NB][136];
    __shared__ alignas(16) unsigned short h_lo[2][NB][136];
    // Double-buffered x tiles (k 0..4 = x, rest zero; stride 40 u16)
    __shared__ alignas(16) unsigned short x_hi[2][NB][40];
    __shared__ alignas(16) unsigned short x_lo[2][NB][40];
    __shared__ alignas(16) float zb[NB][36];   // FC-head z buffer

    const int tid  = threadIdx.x;
    const int b0   = blockIdx.x * NB;
    const int w    = tid >> 6;        // wave 0..7
    const int lane = tid & 63;
    const int n16  = lane & 15;       // A row m (within tile) / B col n / C col n
    const int quad = lane >> 4;       // A k-group / C row-group

    // ---------------- persistent register state ----------------
    bf16x8 aXh[2], aXl[2];            // L0 x K-tile
    bf16x8 a0h[2][2], a0l[2][2];      // L0 h1 K-tiles
    bf16x8 a1h[2][4], a1l[2][4];      // L1 K-tiles over [h1;h2]
    f32x4  bc0[2], bc1[2];            // bias C-init fragments
    float  c0[2] = {0.f, 0.f};        // L0 cell state, one (u,b) per tile
    float  c1[2] = {0.f, 0.f};        // L1 cell state

    #pragma unroll
    for (int t = 0; t < 2; ++t) {
        const int Mt  = w * 2 + t;               // M-tile 0..15
        // A-fragment: lane supplies A[m=n16][k=quad*8+j]
        const int u_a = Mt * 4 + (n16 >> 2);     // permuted: u index of this A row
        const int g_a = n16 & 3;                 // gate index of this A row
        const int r0  = g_a * 64 + u_a;          // original weight row
        float wv[8];
        #pragma unroll
        for (int j = 0; j < 8; ++j) {
            const int k = quad * 8 + j;
            wv[j] = (k < D_IN) ? W_ih0[r0 * D_IN + k] : 0.f;
        }
        split8(wv, aXh[t], aXl[t]);
        #pragma unroll
        for (int kt = 0; kt < 2; ++kt) {
            #pragma unroll
            for (int j = 0; j < 8; ++j) wv[j] = W_hh0[r0 * 64 + kt * 32 + quad * 8 + j];
            split8(wv, a0h[t][kt], a0l[t][kt]);
        }
        #pragma unroll
        for (int kt = 0; kt < 4; ++kt) {
            const int kg = kt * 32 + quad * 8;
            #pragma unroll
            for (int j = 0; j < 8; ++j)
                wv[j] = (kg < 64) ? W_ih1[r0 * 64 + kg + j] : W_hh1[r0 * 64 + (kg - 64) + j];
            split8(wv, a1h[t][kt], a1l[t][kt]);
        }
        // bias: C row quad*4+r -> (u = Mt*4+quad, gate = r) -> orig row r*64+u
        const int u_c = Mt * 4 + quad;
        #pragma unroll
        for (int r = 0; r < 4; ++r) {
            bc0[t][r] = b_ih0[r * 64 + u_c] + b_hh0[r * 64 + u_c];
            bc1[t][r] = b_ih1[r * 64 + u_c] + b_hh1[r * 64 + u_c];
        }
    }

    // ---------------- LDS init ----------------
    for (int i = tid; i < 2 * NB * 136; i += NTHREADS) {
        (&h_hi[0][0][0])[i] = 0;
        (&h_lo[0][0][0])[i] = 0;
    }
    for (int i = tid; i < 2 * NB * 40; i += NTHREADS) {
        (&x_hi[0][0][0])[i] = 0;
        (&x_lo[0][0][0])[i] = 0;
    }
    __syncthreads();
    const int xb = tid / D_IN, xd = tid % D_IN;   // x-staging role (tid < 80)
    if (tid < NB * D_IN) {   // x(t=0) into buffer 0
        const float xv = x[((size_t)(b0 + xb) * T_STEPS) * D_IN + xd];
        const unsigned short xh = f2bf(xv);
        x_hi[0][xb][xd] = xh;
        x_lo[0][xb][xd] = f2bf(xv - bf2f(xh));
    }
    __syncthreads();

    // step s: reads buf[s&1] = {h1(s-1), h2(s-2), x(s)}; computes gates0(s), gates1(s-1)
    //         in-register epilogue; writes h1(s), h2(s-1), x(s+1) into buf[(s+1)&1]
    #pragma unroll 1
    for (int s = 0; s <= T_STEPS; ++s) {
        const int rb = s & 1, wbuf = rb ^ 1;

        float xv = 0.f;   // prefetch x(s+1)
        if (tid < NB * D_IN && (s + 1) < T_STEPS)
            xv = x[((size_t)(b0 + xb) * T_STEPS + (s + 1)) * D_IN + xd];

        const bf16x8 bxh = *reinterpret_cast<const bf16x8*>(&x_hi[rb][n16][quad * 8]);
        const bf16x8 bxl = *reinterpret_cast<const bf16x8*>(&x_lo[rb][n16][quad * 8]);
        bf16x8 bhh[4], bhl[4];
        #pragma unroll
        for (int kt = 0; kt < 4; ++kt) {
            bhh[kt] = *reinterpret_cast<const bf16x8*>(&h_hi[rb][n16][kt * 32 + quad * 8]);
            bhl[kt] = *reinterpret_cast<const bf16x8*>(&h_lo[rb][n16][kt * 32 + quad * 8]);
        }

        #pragma unroll
        for (int t = 0; t < 2; ++t) {
            const int u_c = (w * 2 + t) * 4 + quad;   // this lane's u index, b = n16

            // ---- L0 gates(s) ----
            f32x4 acc = bc0[t];
            acc = MFMA(aXl[t], bxh, acc);
            acc = MFMA(aXh[t], bxl, acc);
            acc = MFMA(aXh[t], bxh, acc);
            #pragma unroll
            for (int kt = 0; kt < 2; ++kt) {
                acc = MFMA(a0l[t][kt], bhh[kt], acc);
                acc = MFMA(a0h[t][kt], bhl[kt], acc);
                acc = MFMA(a0h[t][kt], bhh[kt], acc);
            }
            if (s < T_STEPS) {
                const float i_ = fast_sigmoid(acc[0]);
                const float f_ = fast_sigmoid(acc[1]);
                const float g_ = fast_tanh(acc[2]);
                const float o_ = fast_sigmoid(acc[3]);
                const float c  = f_ * c0[t] + i_ * g_;
                c0[t] = c;
                const float h  = o_ * fast_tanh(c);
                const unsigned short hh = f2bf(h);
                h_hi[wbuf][n16][u_c] = hh;
                h_lo[wbuf][n16][u_c] = f2bf(h - bf2f(hh));
            }

            // ---- L1 gates(s-1) ----
            f32x4 acc1 = bc1[t];
            #pragma unroll
            for (int kt = 0; kt < 4; ++kt) {
                acc1 = MFMA(a1l[t][kt], bhh[kt], acc1);
                acc1 = MFMA(a1h[t][kt], bhl[kt], acc1);
                acc1 = MFMA(a1h[t][kt], bhh[kt], acc1);
            }
            if (s > 0) {
                const float i_ = fast_sigmoid(acc1[0]);
                const float f_ = fast_sigmoid(acc1[1]);
                const float g_ = fast_tanh(acc1[2]);
                const float o_ = fast_sigmoid(acc1[3]);
                const float c  = f_ * c1[t] + i_ * g_;
                c1[t] = c;
                const float h  = o_ * fast_tanh(c);
                const unsigned short hh = f2bf(h);
                h_hi[wbuf][n16][64 + u_c] = hh;
                h_lo[wbuf][n16][64 + u_c] = f2bf(h - bf2f(hh));
            }
        }

        if (tid < NB * D_IN && (s + 1) < T_STEPS) {   // stage x(s+1)
            const unsigned short xh = f2bf(xv);
            x_hi[wbuf][xb][xd] = xh;
            x_lo[wbuf][xb][xd] = f2bf(xv - bf2f(xh));
        }
        __syncthreads();
    }

    // ---------------- FC head: relu(h2_T @ W1^T + b1) @ W2^T + b2 ----------------
    {
        const int fb = (T_STEPS + 1) & 1;   // buffer holding h2(T-1)
        const int bb = tid >> 5;            // 0..15
        const int k  = tid & 31;            // 0..31
        float a = b1[k];
        #pragma unroll 16
        for (int j = 0; j < 64; ++j) {
            const float h = bf2f(h_hi[fb][bb][64 + j]) + bf2f(h_lo[fb][bb][64 + j]);
            a = fmaf(W1[k * 64 + j], h, a);
        }
        zb[bb][k] = fmaxf(a, 0.0f);
    }
    __syncthreads();
    if (tid < NB) {
        float a = b2[0];
        #pragma unroll
        for (int k = 0; k < 32; ++k) a = fmaf(W2[k], zb[tid][k], a);
        out[b0 + tid] = a;
    }
}

extern "C" void kernel_launch(void* const* d_in, const int* in_sizes, int n_in,
                              void* d_out, int out_size, void* d_ws, size_t ws_size,
                              hipStream_t stream) {
    (void)in_sizes; (void)n_in; (void)d_ws; (void)ws_size;
    const float* xp     = (const float*)d_in[0];
    const float* W_ih0  = (const float*)d_in[1];
    const float* W_hh0  = (const float*)d_in[2];
    const float* b_ih0  = (const float*)d_in[3];
    const float* b_hh0  = (const float*)d_in[4];
    const float* W_ih1  = (const float*)d_in[5];
    const float* W_hh1  = (const float*)d_in[6];
    const float* b_ih1  = (const float*)d_in[7];
    const float* b_hh1  = (const float*)d_in[8];
    const float* W1     = (const float*)d_in[9];
    const float* b1     = (const float*)d_in[10];
    const float* W2     = (const float*)d_in[11];
    const float* b2     = (const float*)d_in[12];
    float* outp = (float*)d_out;

    const int nblocks = out_size / NB;   // 4096/16 = 256, one block per CU
    hipLaunchKernelGGL(lstm_stack_mfma2, dim3(nblocks), dim3(NTHREADS), 0, stream,
                       xp, W_ih0, W_hh0, b_ih0, b_hh0,
                       W_ih1, W_hh1, b_ih1, b_hh1,
                       W1, b1, W2, b2, outp);
}

// Round 4
// 979.687 us; speedup vs baseline: 4.8859x; 1.1366x over previous
//
#include <hip/hip_runtime.h>
#include <cstddef>

#define T_STEPS  512
#define D_IN     5
#define NB       16      // batch elements per block
#define NTHREADS 512     // 8 waves; each wave owns 2 L0 M-tiles + 2 L1 M-tiles

typedef __attribute__((ext_vector_type(8))) short bf16x8;   // 8 bf16 (4 VGPRs)
typedef __attribute__((ext_vector_type(4))) float f32x4;    // MFMA C/D

#define MFMA(a, b, c) __builtin_amdgcn_mfma_f32_16x16x32_bf16((a), (b), (c), 0, 0, 0)

__device__ __forceinline__ float fast_sigmoid(float x) {
    return __fdividef(1.0f, 1.0f + __expf(-x));
}
__device__ __forceinline__ float fast_tanh(float x) {
    return 1.0f - __fdividef(2.0f, 1.0f + __expf(2.0f * x));
}

__device__ __forceinline__ unsigned short f2bf(float f) {   // RTNE fp32->bf16 bits
    unsigned int u = __float_as_uint(f);
    u += 0x7FFFu + ((u >> 16) & 1u);
    return (unsigned short)(u >> 16);
}
__device__ __forceinline__ float bf2f(unsigned short h) {
    return __uint_as_float(((unsigned int)h) << 16);
}
__device__ __forceinline__ void split8(const float* wv, bf16x8& hi, bf16x8& lo) {
    #pragma unroll
    for (int j = 0; j < 8; ++j) {
        unsigned short h = f2bf(wv[j]);
        unsigned short l = f2bf(wv[j] - bf2f(h));
        hi[j] = (short)h;
        lo[j] = (short)l;
    }
}

// h-plane swizzle: row = 128 u16 = 16 x 16B blocks; block j of row n lives at
// j ^ (n & 7).  Row stride 64 dw == 0 (mod 32), so the XOR spreads the 16
// column-lanes across all 8 bank-quads; only n vs n+8 alias (2-way = free).
__device__ __forceinline__ int hswz(int n, int col) {
    return (((col >> 3) ^ (n & 7)) << 3) | (col & 7);
}

// Gate-row permutation: MFMA A-row m = (u = m/4, gate = m%4) i.e. original
// weight row gate*64 + u. With C/D layout col=lane&15, row=quad*4+r, each
// lane's f32x4 acc holds (i,f,g,o) for ONE (u,b) pair: cell update is
// register-local.

__global__ __launch_bounds__(NTHREADS, 2)
void lstm_stack_mfma3(const float* __restrict__ x,
                      const float* __restrict__ W_ih0,
                      const float* __restrict__ W_hh0,
                      const float* __restrict__ b_ih0,
                      const float* __restrict__ b_hh0,
                      const float* __restrict__ W_ih1,
                      const float* __restrict__ W_hh1,
                      const float* __restrict__ b_ih1,
                      const float* __restrict__ b_hh1,
                      const float* __restrict__ W1,
                      const float* __restrict__ b1,
                      const float* __restrict__ W2,
                      const float* __restrict__ b2,
                      float* __restrict__ out)
{
    // Double-buffered h plane (hi only), k 0..63 = h1, 64..127 = h2, XOR-swizzled
    __shared__ alignas(16) unsigned short h_hi[2][NB][128];
    // Double-buffered x tiles (k 0..4 = x, rest zero; stride 40 u16)
    __shared__ alignas(16) unsigned short x_hi[2][NB][40];
    __shared__ alignas(16) unsigned short x_lo[2][NB][40];
    __shared__ alignas(16) float h2f[NB][68];   // exact fp32 h2(T-1) for FC head
    __shared__ alignas(16) float zb[NB][36];    // FC-head z buffer

    const int tid  = threadIdx.x;
    const int b0   = blockIdx.x * NB;
    const int w    = tid >> 6;        // wave 0..7
    const int lane = tid & 63;
    const int n16  = lane & 15;       // A row (within tile) / B col / C col
    const int quad = lane >> 4;       // A k-group / C row-group

    // ---------------- persistent register state ----------------
    bf16x8 aXh[2], aXl[2];            // L0 x K-tile (hi/lo weight split)
    bf16x8 a0h[2][2], a0l[2][2];      // L0 h1 K-tiles
    bf16x8 a1h[2][4], a1l[2][4];      // L1 K-tiles over [h1;h2]
    f32x4  bc0[2], bc1[2];            // bias C-init fragments
    float  c0[2] = {0.f, 0.f};        // L0 cell state (u = Mt*4+quad, b = n16)
    float  c1[2] = {0.f, 0.f};        // L1 cell state

    #pragma unroll
    for (int t = 0; t < 2; ++t) {
        const int Mt  = w * 2 + t;               // M-tile 0..15
        const int u_a = Mt * 4 + (n16 >> 2);     // permuted u index of this A row
        const int g_a = n16 & 3;                 // gate index of this A row
        const int r0  = g_a * 64 + u_a;          // original weight row
        float wv[8];
        #pragma unroll
        for (int j = 0; j < 8; ++j) {
            const int k = quad * 8 + j;
            wv[j] = (k < D_IN) ? W_ih0[r0 * D_IN + k] : 0.f;
        }
        split8(wv, aXh[t], aXl[t]);
        #pragma unroll
        for (int kt = 0; kt < 2; ++kt) {
            #pragma unroll
            for (int j = 0; j < 8; ++j) wv[j] = W_hh0[r0 * 64 + kt * 32 + quad * 8 + j];
            split8(wv, a0h[t][kt], a0l[t][kt]);
        }
        #pragma unroll
        for (int kt = 0; kt < 4; ++kt) {
            const int kg = kt * 32 + quad * 8;
            #pragma unroll
            for (int j = 0; j < 8; ++j)
                wv[j] = (kg < 64) ? W_ih1[r0 * 64 + kg + j] : W_hh1[r0 * 64 + (kg - 64) + j];
            split8(wv, a1h[t][kt], a1l[t][kt]);
        }
        const int u_c = Mt * 4 + quad;
        #pragma unroll
        for (int r = 0; r < 4; ++r) {
            bc0[t][r] = b_ih0[r * 64 + u_c] + b_hh0[r * 64 + u_c];
            bc1[t][r] = b_ih1[r * 64 + u_c] + b_hh1[r * 64 + u_c];
        }
    }

    // ---------------- LDS init ----------------
    for (int i = tid; i < 2 * NB * 128; i += NTHREADS) (&h_hi[0][0][0])[i] = 0;
    for (int i = tid; i < 2 * NB * 40; i += NTHREADS) {
        (&x_hi[0][0][0])[i] = 0;
        (&x_lo[0][0][0])[i] = 0;
    }
    __syncthreads();
    const int xb = tid / D_IN, xd = tid % D_IN;   // x-staging role (tid < 80)
    const bool xrole = (tid < NB * D_IN);
    if (xrole) {   // x(t=0) into buffer 0
        const float xv = x[((size_t)(b0 + xb) * T_STEPS) * D_IN + xd];
        const unsigned short xh = f2bf(xv);
        x_hi[0][xb][xd] = xh;
        x_lo[0][xb][xd] = f2bf(xv - bf2f(xh));
    }
    __syncthreads();

    // step s: reads buf[s&1] = {h1(s-1), h2(s-2), x(s)}; computes gates0(s),
    // gates1(s-1); register-local epilogue; writes h1(s), h2(s-1), x(s+1)
    // into buf[(s+1)&1]
    #pragma unroll 1
    for (int s = 0; s <= T_STEPS; ++s) {
        const int rb = s & 1, wbuf = rb ^ 1;

        float xv = 0.f;   // prefetch x(s+1)
        if (xrole && (s + 1) < T_STEPS)
            xv = x[((size_t)(b0 + xb) * T_STEPS + (s + 1)) * D_IN + xd];

        const bf16x8 bxh = *reinterpret_cast<const bf16x8*>(&x_hi[rb][n16][quad * 8]);
        const bf16x8 bxl = *reinterpret_cast<const bf16x8*>(&x_lo[rb][n16][quad * 8]);
        bf16x8 bhh[4];
        #pragma unroll
        for (int kt = 0; kt < 4; ++kt)
            bhh[kt] = *reinterpret_cast<const bf16x8*>(
                &h_hi[rb][n16][((kt * 4 + quad) ^ (n16 & 7)) * 8]);

        f32x4 acc0[2], acc1[2];
        #pragma unroll
        for (int t = 0; t < 2; ++t) {
            f32x4 a = bc0[t];
            a = MFMA(aXl[t], bxh, a);
            a = MFMA(aXh[t], bxl, a);
            a = MFMA(aXh[t], bxh, a);
            #pragma unroll
            for (int kt = 0; kt < 2; ++kt) {
                a = MFMA(a0l[t][kt], bhh[kt], a);
                a = MFMA(a0h[t][kt], bhh[kt], a);
            }
            acc0[t] = a;

            f32x4 b = bc1[t];
            #pragma unroll
            for (int kt = 0; kt < 4; ++kt) {
                b = MFMA(a1l[t][kt], bhh[kt], b);
                b = MFMA(a1h[t][kt], bhh[kt], b);
            }
            acc1[t] = b;
        }

        if (s < T_STEPS) {          // L0 epilogue: h1(s), c1
            #pragma unroll
            for (int t = 0; t < 2; ++t) {
                const int u_c = (w * 2 + t) * 4 + quad;
                const float i_ = fast_sigmoid(acc0[t][0]);
                const float f_ = fast_sigmoid(acc0[t][1]);
                const float g_ = fast_tanh(acc0[t][2]);
                const float o_ = fast_sigmoid(acc0[t][3]);
                const float c  = f_ * c0[t] + i_ * g_;
                c0[t] = c;
                const float h  = o_ * fast_tanh(c);
                h_hi[wbuf][n16][hswz(n16, u_c)] = f2bf(h);
            }
        }
        if (s > 0) {                // L1 epilogue: h2(s-1), c2
            #pragma unroll
            for (int t = 0; t < 2; ++t) {
                const int u_c = (w * 2 + t) * 4 + quad;
                const float i_ = fast_sigmoid(acc1[t][0]);
                const float f_ = fast_sigmoid(acc1[t][1]);
                const float g_ = fast_tanh(acc1[t][2]);
                const float o_ = fast_sigmoid(acc1[t][3]);
                const float c  = f_ * c1[t] + i_ * g_;
                c1[t] = c;
                const float h  = o_ * fast_tanh(c);
                h_hi[wbuf][n16][hswz(n16, 64 + u_c)] = f2bf(h);
                if (s == T_STEPS) h2f[n16][u_c] = h;   // exact h2(T-1) for FC head
            }
        }
        if (xrole && (s + 1) < T_STEPS) {   // stage x(s+1)
            const unsigned short xh = f2bf(xv);
            x_hi[wbuf][xb][xd] = xh;
            x_lo[wbuf][xb][xd] = f2bf(xv - bf2f(xh));
        }
        __syncthreads();
    }

    // ---------------- FC head: relu(h2_T @ W1^T + b1) @ W2^T + b2 ----------------
    {
        const int bb = tid >> 5;            // 0..15
        const int k  = tid & 31;            // 0..31
        float a = b1[k];
        #pragma unroll 16
        for (int j = 0; j < 64; ++j)
            a = fmaf(W1[k * 64 + j], h2f[bb][j], a);
        zb[bb][k] = fmaxf(a, 0.0f);
    }
    __syncthreads();
    if (tid < NB) {
        float a = b2[0];
        #pragma unroll
        for (int k = 0; k < 32; ++k) a = fmaf(W2[k], zb[tid][k], a);
        out[b0 + tid] = a;
    }
}

extern "C" void kernel_launch(void* const* d_in, const int* in_sizes, int n_in,
                              void* d_out, int out_size, void* d_ws, size_t ws_size,
                              hipStream_t stream) {
    (void)in_sizes; (void)n_in; (void)d_ws; (void)ws_size;
    const float* xp     = (const float*)d_in[0];
    const float* W_ih0  = (const float*)d_in[1];
    const float* W_hh0  = (const float*)d_in[2];
    const float* b_ih0  = (const float*)d_in[3];
    const float* b_hh0  = (const float*)d_in[4];
    const float* W_ih1  = (const float*)d_in[5];
    const float* W_hh1  = (const float*)d_in[6];
    const float* b_ih1  = (const float*)d_in[7];
    const float* b_hh1  = (const float*)d_in[8];
    const float* W1     = (const float*)d_in[9];
    const float* b1     = (const float*)d_in[10];
    const float* W2     = (const float*)d_in[11];
    const float* b2     = (const float*)d_in[12];
    float* outp = (float*)d_out;

    const int nblocks = out_size / NB;   // 4096/16 = 256, one block per CU
    hipLaunchKernelGGL(lstm_stack_mfma3, dim3(nblocks), dim3(NTHREADS), 0, stream,
                       xp, W_ih0, W_hh0, b_ih0, b_hh0,
                       W_ih1, W_hh1, b_ih1, b_hh1,
                       W1, b1, W2, b2, outp);
}